// Round 7
// baseline (2394.427 us; speedup 1.0000x reference)
//
#include <hip/hip_runtime.h>
#include <hip/hip_bf16.h>
#include <cstdint>
#include <cstddef>

// GRU: T=256, B=128, I=H=1024, 3H=3072. fp32 in/out.
// Phase 0: convert x, W_ih to bf16 (bandwidth prepass)
// Phase 1: xg = x·W_ih^T + b_ih  (bf16 MFMA GEMM, bf16 output)
// Phase 2: persistent 256-block scan; 8 bg(16 rows) x 32 cg(32 cols).
//   bg = blockIdx&7 -> one XCD per bg (runtime-verified via XCC_ID).
//   h exchange: sc0 (XCD L2) fast / sc0sc1 (MALL) fallback.
//   Step flags: ALWAYS sc0sc1 (MALL) — R6 lesson: sc0-only flag polling
//   can spin on a stale L1 line forever. Split per gate-wave (64/bg).

typedef __attribute__((ext_vector_type(4))) float f32x4;
typedef __attribute__((ext_vector_type(8))) short s16x8;
typedef __attribute__((ext_vector_type(4))) unsigned short u16x4;

static __device__ __forceinline__ unsigned short f2bf(float f) {
  union { float f; unsigned u; } v; v.f = f;
  unsigned u = v.u;
  u += 0x7FFFu + ((u >> 16) & 1u);   // RNE
  return (unsigned short)(u >> 16);
}
static __device__ __forceinline__ float bf2f(unsigned short h) {
  union { unsigned u; float f; } v; v.u = ((unsigned)h) << 16;
  return v.f;
}

// L2-scope (XCD-local) data ops
static __device__ __forceinline__ s16x8 ld16_l2(const unsigned short* p) {
  s16x8 r;
  asm volatile("global_load_dwordx4 %0, %1, off sc0" : "=v"(r) : "v"(p) : "memory");
  return r;
}
static __device__ __forceinline__ void st2_l2(unsigned short* p, unsigned short v) {
  unsigned vv = v;
  asm volatile("global_store_short %0, %1, off sc0" :: "v"(p), "v"(vv) : "memory");
}
// device-scope (MALL) data ops
static __device__ __forceinline__ s16x8 ld16_mall(const unsigned short* p) {
  s16x8 r;
  asm volatile("global_load_dwordx4 %0, %1, off sc0 sc1" : "=v"(r) : "v"(p) : "memory");
  return r;
}
static __device__ __forceinline__ void st2_mall(unsigned short* p, unsigned short v) {
  unsigned vv = v;
  asm volatile("global_store_short %0, %1, off sc0 sc1" :: "v"(p), "v"(vv) : "memory");
}
// flags: ALWAYS MALL scope
static __device__ __forceinline__ void st_flag(unsigned int* p, unsigned v) {
  asm volatile("global_store_dword %0, %1, off sc0 sc1" :: "v"(p), "v"(v) : "memory");
}
static __device__ __forceinline__ unsigned ld_flag(const unsigned int* p) {
  unsigned r;
  asm volatile("global_load_dword %0, %1, off sc0 sc1\n\ts_waitcnt vmcnt(0)"
               : "=v"(r) : "v"(p) : "memory");
  return r;
}

// ---------------- Phase 0: f32 -> bf16 convert ----------------
__global__ __launch_bounds__(256)
void cvt_bf16(const float* __restrict__ src, unsigned short* __restrict__ dst, int n4) {
  int i = blockIdx.x * 256 + threadIdx.x;
  int stride = gridDim.x * 256;
  for (; i < n4; i += stride) {
    f32x4 v = ((const f32x4*)src)[i];
    u16x4 o = { f2bf(v.x), f2bf(v.y), f2bf(v.z), f2bf(v.w) };
    ((u16x4*)dst)[i] = o;
  }
}

// ---------------- Phase 1: xg GEMM (bf16 in, bf16 out) ----------------
__global__ __launch_bounds__(256)
void xg_gemm(const unsigned short* __restrict__ Xb,  // [32768,1024] bf16
             const unsigned short* __restrict__ Wb,  // [3072,1024] bf16
             const float* __restrict__ bias,         // [3072]
             unsigned short* __restrict__ xg)        // [32768,3072] bf16
{
  __shared__ unsigned short Al[128][72];
  __shared__ unsigned short Bl[128][72];
  const int tid = threadIdx.x;
  const int lane = tid & 63;
  const int wv = tid >> 6;
  const int wm = (wv & 1) * 64;
  const int wn = (wv >> 1) * 64;
  const int m0 = blockIdx.y * 128;
  const int n0 = blockIdx.x * 128;
  const int r16 = lane & 15, r4 = lane >> 4;
  f32x4 acc[4][4] = {};

  for (int k0 = 0; k0 < 1024; k0 += 64) {
    __syncthreads();
    #pragma unroll
    for (int j = 0; j < 4; ++j) {
      int idx = j * 256 + tid;            // 1024 chunks of 16B = 128 rows x 8
      int row = idx >> 3, c8 = idx & 7;
      *(s16x8*)&Al[row][c8 * 8] = *(const s16x8*)(Xb + (size_t)(m0 + row) * 1024 + k0 + c8 * 8);
      *(s16x8*)&Bl[row][c8 * 8] = *(const s16x8*)(Wb + (size_t)(n0 + row) * 1024 + k0 + c8 * 8);
    }
    __syncthreads();
    #pragma unroll
    for (int kk = 0; kk < 64; kk += 32) {
      s16x8 af[4], bf[4];
      #pragma unroll
      for (int mi = 0; mi < 4; ++mi)
        af[mi] = *(const s16x8*)&Al[wm + mi * 16 + r16][kk + r4 * 8];
      #pragma unroll
      for (int ni = 0; ni < 4; ++ni)
        bf[ni] = *(const s16x8*)&Bl[wn + ni * 16 + r16][kk + r4 * 8];
      #pragma unroll
      for (int mi = 0; mi < 4; ++mi)
        #pragma unroll
        for (int ni = 0; ni < 4; ++ni)
          acc[mi][ni] = __builtin_amdgcn_mfma_f32_16x16x32_bf16(af[mi], bf[ni], acc[mi][ni], 0, 0, 0);
    }
  }
  #pragma unroll
  for (int ni = 0; ni < 4; ++ni) {
    float bv = bias[n0 + wn + ni * 16 + r16];
    #pragma unroll
    for (int mi = 0; mi < 4; ++mi) {
      #pragma unroll
      for (int r = 0; r < 4; ++r) {
        int m = m0 + wm + mi * 16 + r4 * 4 + r;
        int n = n0 + wn + ni * 16 + r16;
        xg[(size_t)m * 3072 + n] = f2bf(acc[mi][ni][r] + bv);
      }
    }
  }
}

// ---------------- Phase 2: persistent GRU scan ----------------
// 256 blocks: bg = id&7 (16 batch rows), cg = id>>3 (32 h-cols).
// 8 waves: ks = wv>>1 (K-quarter), nt = wv&1 (16-col half).
__global__ __launch_bounds__(512, 2)
void gru_scan(const unsigned short* __restrict__ xg,  // [32768,3072] bf16
              const float* __restrict__ Whh,          // [3072,1024]
              const float* __restrict__ bhh,          // [3072]
              float* __restrict__ out,                // [256,128,1024]
              unsigned short* __restrict__ hbc,       // 2 x [128][1024] bf16
              unsigned int* __restrict__ bar)         // flags/det regions
{
  __shared__ char hraw[32768];           // swizzled [16][1024] bf16 h tile
  __shared__ float part[6][3][64][4];    // K-partials, lane-dense
  __shared__ int fastsh;

  const int tid = threadIdx.x;
  const int lane = tid & 63;
  const int wv = tid >> 6;
  const int id = blockIdx.x;
  const int bg = id & 7;
  const int cg = id >> 3;
  const int c0 = cg * 32;
  const int b0 = bg * 16;
  const int r16 = lane & 15, r4 = lane >> 4;
  const int ks = wv >> 1, nt = wv & 1;

  unsigned int* sflags = bar + bg * 256;          // 64 step-flags per bg
  unsigned int* dflags = bar + 2048 + bg * 256;   // 32 det-flags per bg

  // ---- XCD co-residency detection (HW_REG_XCC_ID) ----
  unsigned myxcc = (__builtin_amdgcn_s_getreg(63508) & 0xFu) | 0x100u;
  if (tid == 0) st_flag(dflags + cg, myxcc);
  if (wv == 0) {
    unsigned v;
    for (;;) {
      v = ld_flag(dflags + (lane & 31));
      if (__ballot(v < 0x100u) == 0) break;
      __builtin_amdgcn_s_sleep(1);
    }
    int bad = (v != myxcc);
    if (tid == 0) fastsh = (__ballot(bad) == 0) ? 1 : 0;
  }
  __syncthreads();
  const bool fast = (fastsh != 0);

  // ---- W_hh fragments in registers: bw[gate][kc] ----
  s16x8 bw[3][8];
  #pragma unroll
  for (int n = 0; n < 3; ++n) {
    const float* wrow = Whh + (size_t)(n * 1024 + c0 + nt * 16 + r16) * 1024;
    #pragma unroll
    for (int kc = 0; kc < 8; ++kc) {
      int k = ks * 256 + kc * 32 + r4 * 8;
      f32x4 v0 = *(const f32x4*)(wrow + k);
      f32x4 v1 = *(const f32x4*)(wrow + k + 4);
      s16x8 f;
      f[0] = (short)f2bf(v0.x); f[1] = (short)f2bf(v0.y);
      f[2] = (short)f2bf(v0.z); f[3] = (short)f2bf(v0.w);
      f[4] = (short)f2bf(v1.x); f[5] = (short)f2bf(v1.y);
      f[6] = (short)f2bf(v1.z); f[7] = (short)f2bf(v1.w);
      bw[n][kc] = f;
    }
  }

  // gate-phase constants (meaningful for wv<2)
  const int gcol = c0 + nt * 16 + r16;
  const float bR = bhh[gcol];
  const float bZ = bhh[1024 + gcol];
  const float bN = bhh[2048 + gcol];
  float hprev[4] = {0.f, 0.f, 0.f, 0.f};
  float xqr[4], xqz[4], xqn[4];
  if (wv < 2) {
    #pragma unroll
    for (int r = 0; r < 4; ++r) {
      size_t xi = ((size_t)(b0 + r4 * 4 + r)) * 3072 + gcol;
      xqr[r] = bf2f(xg[xi]); xqz[r] = bf2f(xg[xi + 1024]); xqn[r] = bf2f(xg[xi + 2048]);
    }
  }

  // zero h tile (h0 = 0)
  #pragma unroll
  for (int i = 0; i < 4; ++i)
    *(f32x4*)(hraw + tid * 64 + i * 16) = (f32x4){0.f, 0.f, 0.f, 0.f};
  __syncthreads();

  // A-frag read addressing (swizzled)
  const int arow = lane & 15;
  const int aswz = (arow & 7) << 4;
  const int abase = arow * 2048;
  const int g16 = (lane >> 4) * 16;

  // staging addressing: rows {i*4+ks}, colbyte = nt*1024 + lane*16
  const int scb = nt * 1024 + lane * 16;
  int s_goff[4], s_loff[4];
  #pragma unroll
  for (int i = 0; i < 4; ++i) {
    int row = i * 4 + ks;
    s_goff[i] = (b0 + row) * 1024 + (scb >> 1);
    s_loff[i] = row * 2048 + (scb ^ ((row & 7) << 4));
  }

  for (int t = 0; t < 256; ++t) {
    // ---- MFMA over h[t] ----
    f32x4 a0 = {0.f,0.f,0.f,0.f}, a1 = a0, a2 = a0;
    #pragma unroll
    for (int kc = 0; kc < 8; ++kc) {
      s16x8 a = *(const s16x8*)(hraw + abase + ((ks * 512 + kc * 64 + g16) ^ aswz));
      a0 = __builtin_amdgcn_mfma_f32_16x16x32_bf16(a, bw[0][kc], a0, 0, 0, 0);
      a1 = __builtin_amdgcn_mfma_f32_16x16x32_bf16(a, bw[1][kc], a1, 0, 0, 0);
      a2 = __builtin_amdgcn_mfma_f32_16x16x32_bf16(a, bw[2][kc], a2, 0, 0, 0);
    }
    if (ks > 0) {
      int pi = (ks - 1) * 2 + nt;
      *(f32x4*)&part[pi][0][lane][0] = a0;
      *(f32x4*)&part[pi][1][lane][0] = a1;
      *(f32x4*)&part[pi][2][lane][0] = a2;
    }
    __syncthreads();                                   // S1

    if (ks == 0) {
      #pragma unroll
      for (int kx = 0; kx < 3; ++kx) {
        a0 += *(const f32x4*)&part[kx * 2 + nt][0][lane][0];
        a1 += *(const f32x4*)&part[kx * 2 + nt][1][lane][0];
        a2 += *(const f32x4*)&part[kx * 2 + nt][2][lane][0];
      }
      unsigned short* wH = hbc + (size_t)((t + 1) & 1) * 131072;
      float hnew[4];
      #pragma unroll
      for (int r = 0; r < 4; ++r) {
        float rg = 1.f / (1.f + expf(-(xqr[r] + a0[r] + bR)));
        float zg = 1.f / (1.f + expf(-(xqz[r] + a1[r] + bZ)));
        float ng = tanhf(xqn[r] + rg * (a2[r] + bN));
        float h = (1.f - zg) * ng + zg * hprev[r];
        hprev[r] = h; hnew[r] = h;
        out[(size_t)t * 131072 + (size_t)(b0 + r4 * 4 + r) * 1024 + gcol] = h;
      }
      // h broadcast, per-wave drain, then THIS WAVE's flag (no block sync)
      if (fast) {
        #pragma unroll
        for (int r = 0; r < 4; ++r)
          st2_l2(wH + (size_t)(b0 + r4 * 4 + r) * 1024 + gcol, f2bf(hnew[r]));
      } else {
        #pragma unroll
        for (int r = 0; r < 4; ++r)
          st2_mall(wH + (size_t)(b0 + r4 * 4 + r) * 1024 + gcol, f2bf(hnew[r]));
      }
      asm volatile("s_waitcnt vmcnt(0)" ::: "memory");
      if (lane == 0) st_flag(sflags + cg * 2 + nt, (unsigned)(t + 1));
    }

    if (t < 255) {
      // xg prefetch for t+1 overlaps the poll wait
      if (wv < 2) {
        #pragma unroll
        for (int r = 0; r < 4; ++r) {
          size_t xi = ((size_t)((t + 1) * 128 + b0 + r4 * 4 + r)) * 3072 + gcol;
          xqr[r] = bf2f(xg[xi]); xqz[r] = bf2f(xg[xi + 1024]); xqn[r] = bf2f(xg[xi + 2048]);
        }
      }
      // wv7 polls all 64 gate-wave flags of this bg (MALL scope)
      if (wv == 7) {
        unsigned tgt = (unsigned)(t + 1);
        for (;;) {
          unsigned v = ld_flag(sflags + lane);
          if (__ballot(v < tgt) == 0) break;
          __builtin_amdgcn_s_sleep(1);
        }
      }
      __syncthreads();                                 // S2

      // stage h[t+1] into LDS (swizzled)
      const unsigned short* hs = hbc + (size_t)((t + 1) & 1) * 131072;
      s16x8 v0, v1, v2, v3;
      if (fast) {
        v0 = ld16_l2(hs + s_goff[0]); v1 = ld16_l2(hs + s_goff[1]);
        v2 = ld16_l2(hs + s_goff[2]); v3 = ld16_l2(hs + s_goff[3]);
      } else {
        v0 = ld16_mall(hs + s_goff[0]); v1 = ld16_mall(hs + s_goff[1]);
        v2 = ld16_mall(hs + s_goff[2]); v3 = ld16_mall(hs + s_goff[3]);
      }
      asm volatile("s_waitcnt vmcnt(0)" ::: "memory");
      *(s16x8*)(hraw + s_loff[0]) = v0;
      *(s16x8*)(hraw + s_loff[1]) = v1;
      *(s16x8*)(hraw + s_loff[2]) = v2;
      *(s16x8*)(hraw + s_loff[3]) = v3;
      __syncthreads();                                 // S3
    }
  }
}

extern "C" void kernel_launch(void* const* d_in, const int* in_sizes, int n_in,
                              void* d_out, int out_size, void* d_ws, size_t ws_size,
                              hipStream_t stream) {
  const float* x   = (const float*)d_in[0];
  const float* wih = (const float*)d_in[1];
  const float* whh = (const float*)d_in[2];
  const float* bih = (const float*)d_in[3];
  const float* bhh = (const float*)d_in[4];
  float* out = (float*)d_out;

  char* ws = (char*)d_ws;
  unsigned short* xg  = (unsigned short*)ws;                      // 192 MiB
  unsigned short* xbf = (unsigned short*)(ws + 201326592);        // 64 MiB
  unsigned short* wbf = (unsigned short*)(ws + 268435456);        // 6 MiB
  unsigned short* hbc = (unsigned short*)(ws + 274726912);        // 512 KiB
  unsigned int*   bar = (unsigned int*)(ws + 275251200);          // 16 KiB

  hipMemsetAsync(bar, 0, 16384, stream);
  cvt_bf16<<<2048, 256, 0, stream>>>(x, xbf, 32768 * 1024 / 4);
  cvt_bf16<<<768, 256, 0, stream>>>(wih, wbf, 3072 * 1024 / 4);
  xg_gemm<<<dim3(24, 256), 256, 0, stream>>>(xbf, wbf, bih, xg);
  gru_scan<<<256, 512, 0, stream>>>(xg, whh, bhh, out, hbc, bar);
}

// Round 8
// 1158.324 us; speedup vs baseline: 2.0671x; 2.0671x over previous
//
#include <hip/hip_runtime.h>
#include <hip/hip_bf16.h>
#include <cstdint>
#include <cstddef>

// GRU: T=256, B=128, I=H=1024, 3H=3072. fp32 in/out.
// Phase 0: convert x, W_ih to bf16 (bandwidth prepass)
// Phase 1: xg = x·W_ih^T + b_ih  (bf16 MFMA GEMM, bf16 output)
// Phase 2: persistent 256-block scan; 8 bg(16 rows) x 32 cg(32 cols).
//   Scan structure = R5 (proven): S1 / gate+drain / barrier / tid0 flag /
//   prefetch+poll / S2 / stage / S3.
//   R8 change: step flags are ATOMICS. Fast mode (XCD co-resident, runtime
//   verified): no-sc1 atomics execute at the shared XCD L2 (~300cyc, never
//   L1-stale - atomics bypass vL1; also immune to cross-launch replay
//   staleness). Fallback: same atomics with sc1 (MALL). R6 lesson stands:
//   plain sc0 LOADS may spin on stale L1 forever - never poll with loads.

typedef __attribute__((ext_vector_type(4))) float f32x4;
typedef __attribute__((ext_vector_type(8))) short s16x8;
typedef __attribute__((ext_vector_type(4))) unsigned short u16x4;

static __device__ __forceinline__ unsigned short f2bf(float f) {
  union { float f; unsigned u; } v; v.f = f;
  unsigned u = v.u;
  u += 0x7FFFu + ((u >> 16) & 1u);   // RNE
  return (unsigned short)(u >> 16);
}
static __device__ __forceinline__ float bf2f(unsigned short h) {
  union { unsigned u; float f; } v; v.u = ((unsigned)h) << 16;
  return v.f;
}

// L2-scope (XCD-local) data ops
static __device__ __forceinline__ s16x8 ld16_l2(const unsigned short* p) {
  s16x8 r;
  asm volatile("global_load_dwordx4 %0, %1, off sc0" : "=v"(r) : "v"(p) : "memory");
  return r;
}
static __device__ __forceinline__ void st2_l2(unsigned short* p, unsigned short v) {
  unsigned vv = v;
  asm volatile("global_store_short %0, %1, off sc0" :: "v"(p), "v"(vv) : "memory");
}
// device-scope (MALL) data ops
static __device__ __forceinline__ s16x8 ld16_mall(const unsigned short* p) {
  s16x8 r;
  asm volatile("global_load_dwordx4 %0, %1, off sc0 sc1" : "=v"(r) : "v"(p) : "memory");
  return r;
}
static __device__ __forceinline__ void st2_mall(unsigned short* p, unsigned short v) {
  unsigned vv = v;
  asm volatile("global_store_short %0, %1, off sc0 sc1" :: "v"(p), "v"(vv) : "memory");
}
// det flags (once per launch): MALL loads/stores
static __device__ __forceinline__ void st_flag(unsigned int* p, unsigned v) {
  asm volatile("global_store_dword %0, %1, off sc0 sc1" :: "v"(p), "v"(v) : "memory");
}
static __device__ __forceinline__ unsigned ld_flag(const unsigned int* p) {
  unsigned r;
  asm volatile("global_load_dword %0, %1, off sc0 sc1\n\ts_waitcnt vmcnt(0)"
               : "=v"(r) : "v"(p) : "memory");
  return r;
}
// step-flag atomics: arrival (no-return swap), poll (add-0 returning old)
static __device__ __forceinline__ void arrive_l2(unsigned int* p, unsigned v) {
  asm volatile("global_atomic_swap %0, %1, off" :: "v"(p), "v"(v) : "memory");
}
static __device__ __forceinline__ void arrive_mall(unsigned int* p, unsigned v) {
  asm volatile("global_atomic_swap %0, %1, off sc1" :: "v"(p), "v"(v) : "memory");
}
static __device__ __forceinline__ unsigned poll_l2(unsigned int* p, unsigned zero) {
  unsigned old;
  asm volatile("global_atomic_add %0, %1, %2, off sc0\n\ts_waitcnt vmcnt(0)"
               : "=v"(old) : "v"(p), "v"(zero) : "memory");
  return old;
}
static __device__ __forceinline__ unsigned poll_mall(unsigned int* p, unsigned zero) {
  unsigned old;
  asm volatile("global_atomic_add %0, %1, %2, off sc0 sc1\n\ts_waitcnt vmcnt(0)"
               : "=v"(old) : "v"(p), "v"(zero) : "memory");
  return old;
}

// ---------------- Phase 0: f32 -> bf16 convert ----------------
__global__ __launch_bounds__(256)
void cvt_bf16(const float* __restrict__ src, unsigned short* __restrict__ dst, int n4) {
  int i = blockIdx.x * 256 + threadIdx.x;
  int stride = gridDim.x * 256;
  for (; i < n4; i += stride) {
    f32x4 v = ((const f32x4*)src)[i];
    u16x4 o = { f2bf(v.x), f2bf(v.y), f2bf(v.z), f2bf(v.w) };
    ((u16x4*)dst)[i] = o;
  }
}

// ---------------- Phase 1: xg GEMM (bf16 in, bf16 out) ----------------
__global__ __launch_bounds__(256)
void xg_gemm(const unsigned short* __restrict__ Xb,  // [32768,1024] bf16
             const unsigned short* __restrict__ Wb,  // [3072,1024] bf16
             const float* __restrict__ bias,         // [3072]
             unsigned short* __restrict__ xg)        // [32768,3072] bf16
{
  __shared__ unsigned short Al[128][72];
  __shared__ unsigned short Bl[128][72];
  const int tid = threadIdx.x;
  const int lane = tid & 63;
  const int wv = tid >> 6;
  const int wm = (wv & 1) * 64;
  const int wn = (wv >> 1) * 64;
  const int m0 = blockIdx.y * 128;
  const int n0 = blockIdx.x * 128;
  const int r16 = lane & 15, r4 = lane >> 4;
  f32x4 acc[4][4] = {};

  for (int k0 = 0; k0 < 1024; k0 += 64) {
    __syncthreads();
    #pragma unroll
    for (int j = 0; j < 4; ++j) {
      int idx = j * 256 + tid;
      int row = idx >> 3, c8 = idx & 7;
      *(s16x8*)&Al[row][c8 * 8] = *(const s16x8*)(Xb + (size_t)(m0 + row) * 1024 + k0 + c8 * 8);
      *(s16x8*)&Bl[row][c8 * 8] = *(const s16x8*)(Wb + (size_t)(n0 + row) * 1024 + k0 + c8 * 8);
    }
    __syncthreads();
    #pragma unroll
    for (int kk = 0; kk < 64; kk += 32) {
      s16x8 af[4], bf[4];
      #pragma unroll
      for (int mi = 0; mi < 4; ++mi)
        af[mi] = *(const s16x8*)&Al[wm + mi * 16 + r16][kk + r4 * 8];
      #pragma unroll
      for (int ni = 0; ni < 4; ++ni)
        bf[ni] = *(const s16x8*)&Bl[wn + ni * 16 + r16][kk + r4 * 8];
      #pragma unroll
      for (int mi = 0; mi < 4; ++mi)
        #pragma unroll
        for (int ni = 0; ni < 4; ++ni)
          acc[mi][ni] = __builtin_amdgcn_mfma_f32_16x16x32_bf16(af[mi], bf[ni], acc[mi][ni], 0, 0, 0);
    }
  }
  #pragma unroll
  for (int ni = 0; ni < 4; ++ni) {
    float bv = bias[n0 + wn + ni * 16 + r16];
    #pragma unroll
    for (int mi = 0; mi < 4; ++mi) {
      #pragma unroll
      for (int r = 0; r < 4; ++r) {
        int m = m0 + wm + mi * 16 + r4 * 4 + r;
        int n = n0 + wn + ni * 16 + r16;
        xg[(size_t)m * 3072 + n] = f2bf(acc[mi][ni][r] + bv);
      }
    }
  }
}

// ---------------- Phase 2: persistent GRU scan ----------------
// 256 blocks: bg = id&7 (16 batch rows), cg = id>>3 (32 h-cols).
// 8 waves: ks = wv>>1 (K-quarter), nt = wv&1 (16-col half).
__global__ __launch_bounds__(512, 2)
void gru_scan(const unsigned short* __restrict__ xg,  // [32768,3072] bf16
              const float* __restrict__ Whh,          // [3072,1024]
              const float* __restrict__ bhh,          // [3072]
              float* __restrict__ out,                // [256,128,1024]
              unsigned short* __restrict__ hbc,       // 2 x [128][1024] bf16
              unsigned int* __restrict__ bar)         // flag regions
{
  __shared__ char hraw[32768];           // swizzled [16][1024] bf16 h tile
  __shared__ float part[6][3][64][4];    // K-partials, lane-dense
  __shared__ int fastsh;

  const int tid = threadIdx.x;
  const int lane = tid & 63;
  const int wv = tid >> 6;
  const int id = blockIdx.x;
  const int bg = id & 7;
  const int cg = id >> 3;
  const int c0 = cg * 32;
  const int b0 = bg * 16;
  const int r16 = lane & 15, r4 = lane >> 4;
  const int ks = wv >> 1, nt = wv & 1;

  // step flags: one 128B line per (bg,cg) cell
  unsigned int* sflags = bar + (size_t)(bg * 32) * 32;   // + cg*32
  unsigned int* dflags = bar + 8192 + bg * 32;           // dense det flags

  // ---- XCD co-residency detection (HW_REG_XCC_ID) ----
  unsigned myxcc = (__builtin_amdgcn_s_getreg(63508) & 0xFu) | 0x100u;
  if (tid == 0) st_flag(dflags + cg, myxcc);
  if (wv == 0) {
    unsigned v;
    for (;;) {
      v = ld_flag(dflags + (lane & 31));
      if (__ballot(v < 0x100u) == 0) break;
      __builtin_amdgcn_s_sleep(1);
    }
    int bad = (v != myxcc);
    if (tid == 0) fastsh = (__ballot(bad) == 0) ? 1 : 0;
  }
  __syncthreads();
  const bool fast = (fastsh != 0);

  // ---- W_hh fragments in registers: bw[gate][kc] ----
  s16x8 bw[3][8];
  #pragma unroll
  for (int n = 0; n < 3; ++n) {
    const float* wrow = Whh + (size_t)(n * 1024 + c0 + nt * 16 + r16) * 1024;
    #pragma unroll
    for (int kc = 0; kc < 8; ++kc) {
      int k = ks * 256 + kc * 32 + r4 * 8;
      f32x4 v0 = *(const f32x4*)(wrow + k);
      f32x4 v1 = *(const f32x4*)(wrow + k + 4);
      s16x8 f;
      f[0] = (short)f2bf(v0.x); f[1] = (short)f2bf(v0.y);
      f[2] = (short)f2bf(v0.z); f[3] = (short)f2bf(v0.w);
      f[4] = (short)f2bf(v1.x); f[5] = (short)f2bf(v1.y);
      f[6] = (short)f2bf(v1.z); f[7] = (short)f2bf(v1.w);
      bw[n][kc] = f;
    }
  }

  // gate-phase constants (meaningful for wv<2)
  const int gcol = c0 + nt * 16 + r16;
  const float bR = bhh[gcol];
  const float bZ = bhh[1024 + gcol];
  const float bN = bhh[2048 + gcol];
  float hprev[4] = {0.f, 0.f, 0.f, 0.f};
  float xqr[4], xqz[4], xqn[4];
  if (wv < 2) {
    #pragma unroll
    for (int r = 0; r < 4; ++r) {
      size_t xi = ((size_t)(b0 + r4 * 4 + r)) * 3072 + gcol;
      xqr[r] = bf2f(xg[xi]); xqz[r] = bf2f(xg[xi + 1024]); xqn[r] = bf2f(xg[xi + 2048]);
    }
  }

  // zero h tile (h0 = 0)
  #pragma unroll
  for (int i = 0; i < 4; ++i)
    *(f32x4*)(hraw + tid * 64 + i * 16) = (f32x4){0.f, 0.f, 0.f, 0.f};
  __syncthreads();

  // A-frag read addressing (swizzled)
  const int arow = lane & 15;
  const int aswz = (arow & 7) << 4;
  const int abase = arow * 2048;
  const int g16 = (lane >> 4) * 16;

  // staging addressing: rows {i*4+ks}, colbyte = nt*1024 + lane*16
  const int scb = nt * 1024 + lane * 16;
  int s_goff[4], s_loff[4];
  #pragma unroll
  for (int i = 0; i < 4; ++i) {
    int row = i * 4 + ks;
    s_goff[i] = (b0 + row) * 1024 + (scb >> 1);
    s_loff[i] = row * 2048 + (scb ^ ((row & 7) << 4));
  }

  for (int t = 0; t < 256; ++t) {
    // ---- MFMA over h[t] ----
    f32x4 a0 = {0.f,0.f,0.f,0.f}, a1 = a0, a2 = a0;
    #pragma unroll
    for (int kc = 0; kc < 8; ++kc) {
      s16x8 a = *(const s16x8*)(hraw + abase + ((ks * 512 + kc * 64 + g16) ^ aswz));
      a0 = __builtin_amdgcn_mfma_f32_16x16x32_bf16(a, bw[0][kc], a0, 0, 0, 0);
      a1 = __builtin_amdgcn_mfma_f32_16x16x32_bf16(a, bw[1][kc], a1, 0, 0, 0);
      a2 = __builtin_amdgcn_mfma_f32_16x16x32_bf16(a, bw[2][kc], a2, 0, 0, 0);
    }
    if (ks > 0) {
      int pi = (ks - 1) * 2 + nt;
      *(f32x4*)&part[pi][0][lane][0] = a0;
      *(f32x4*)&part[pi][1][lane][0] = a1;
      *(f32x4*)&part[pi][2][lane][0] = a2;
    }
    __syncthreads();                                   // S1

    if (ks == 0) {
      #pragma unroll
      for (int kx = 0; kx < 3; ++kx) {
        a0 += *(const f32x4*)&part[kx * 2 + nt][0][lane][0];
        a1 += *(const f32x4*)&part[kx * 2 + nt][1][lane][0];
        a2 += *(const f32x4*)&part[kx * 2 + nt][2][lane][0];
      }
      unsigned short* wH = hbc + (size_t)((t + 1) & 1) * 131072;
      float hnew[4];
      #pragma unroll
      for (int r = 0; r < 4; ++r) {
        float rg = 1.f / (1.f + expf(-(xqr[r] + a0[r] + bR)));
        float zg = 1.f / (1.f + expf(-(xqz[r] + a1[r] + bZ)));
        float ng = tanhf(xqn[r] + rg * (a2[r] + bN));
        float h = (1.f - zg) * ng + zg * hprev[r];
        hprev[r] = h; hnew[r] = h;
        out[(size_t)t * 131072 + (size_t)(b0 + r4 * 4 + r) * 1024 + gcol] = h;
      }
      if (fast) {
        #pragma unroll
        for (int r = 0; r < 4; ++r)
          st2_l2(wH + (size_t)(b0 + r4 * 4 + r) * 1024 + gcol, f2bf(hnew[r]));
      } else {
        #pragma unroll
        for (int r = 0; r < 4; ++r)
          st2_mall(wH + (size_t)(b0 + r4 * 4 + r) * 1024 + gcol, f2bf(hnew[r]));
      }
      asm volatile("s_waitcnt vmcnt(0)" ::: "memory");
    }
    __syncthreads();                                   // post-gate barrier (R5)

    if (tid == 0) {
      if (fast) arrive_l2(sflags + cg * 32, (unsigned)(t + 1));
      else      arrive_mall(sflags + cg * 32, (unsigned)(t + 1));
    }

    if (t < 255) {
      // xg prefetch for t+1 overlaps the poll wait
      if (wv < 2) {
        #pragma unroll
        for (int r = 0; r < 4; ++r) {
          size_t xi = ((size_t)((t + 1) * 128 + b0 + r4 * 4 + r)) * 3072 + gcol;
          xqr[r] = bf2f(xg[xi]); xqz[r] = bf2f(xg[xi + 1024]); xqn[r] = bf2f(xg[xi + 2048]);
        }
      }
      // wv7 polls 32 per-block flags via L2/MALL atomics
      if (wv == 7 && lane < 32) {
        unsigned tgt = (unsigned)(t + 1);
        unsigned int* fp = sflags + lane * 32;
        if (fast) {
          for (;;) {
            unsigned v = poll_l2(fp, 0u);
            if (__ballot(v < tgt) == 0) break;
          }
        } else {
          for (;;) {
            unsigned v = poll_mall(fp, 0u);
            if (__ballot(v < tgt) == 0) break;
            __builtin_amdgcn_s_sleep(1);
          }
        }
      }
      __syncthreads();                                 // S2

      // stage h[t+1] into LDS (swizzled)
      const unsigned short* hs = hbc + (size_t)((t + 1) & 1) * 131072;
      s16x8 v0, v1, v2, v3;
      if (fast) {
        v0 = ld16_l2(hs + s_goff[0]); v1 = ld16_l2(hs + s_goff[1]);
        v2 = ld16_l2(hs + s_goff[2]); v3 = ld16_l2(hs + s_goff[3]);
      } else {
        v0 = ld16_mall(hs + s_goff[0]); v1 = ld16_mall(hs + s_goff[1]);
        v2 = ld16_mall(hs + s_goff[2]); v3 = ld16_mall(hs + s_goff[3]);
      }
      asm volatile("s_waitcnt vmcnt(0)" ::: "memory");
      *(s16x8*)(hraw + s_loff[0]) = v0;
      *(s16x8*)(hraw + s_loff[1]) = v1;
      *(s16x8*)(hraw + s_loff[2]) = v2;
      *(s16x8*)(hraw + s_loff[3]) = v3;
      __syncthreads();                                 // S3
    }
  }
}

extern "C" void kernel_launch(void* const* d_in, const int* in_sizes, int n_in,
                              void* d_out, int out_size, void* d_ws, size_t ws_size,
                              hipStream_t stream) {
  const float* x   = (const float*)d_in[0];
  const float* wih = (const float*)d_in[1];
  const float* whh = (const float*)d_in[2];
  const float* bih = (const float*)d_in[3];
  const float* bhh = (const float*)d_in[4];
  float* out = (float*)d_out;

  char* ws = (char*)d_ws;
  unsigned short* xg  = (unsigned short*)ws;                      // 192 MiB
  unsigned short* xbf = (unsigned short*)(ws + 201326592);        // 64 MiB
  unsigned short* wbf = (unsigned short*)(ws + 268435456);        // 6 MiB
  unsigned short* hbc = (unsigned short*)(ws + 274726912);        // 512 KiB
  unsigned int*   bar = (unsigned int*)(ws + 275251200);          // 40 KiB

  hipMemsetAsync(bar, 0, 40960, stream);
  cvt_bf16<<<2048, 256, 0, stream>>>(x, xbf, 32768 * 1024 / 4);
  cvt_bf16<<<768, 256, 0, stream>>>(wih, wbf, 3072 * 1024 / 4);
  xg_gemm<<<dim3(24, 256), 256, 0, stream>>>(xbf, wbf, bih, xg);
  gru_scan<<<256, 512, 0, stream>>>(xg, whh, bhh, out, hbc, bar);
}

// Round 9
// 1080.664 us; speedup vs baseline: 2.2157x; 1.0719x over previous
//
#include <hip/hip_runtime.h>
#include <hip/hip_bf16.h>
#include <cstdint>
#include <cstddef>

// GRU: T=256, B=128, I=H=1024, 3H=3072. fp32 in/out.
// Phase 0: convert x, W_ih to bf16. Phase 1: xg GEMM (bf16). Phase 2: scan.
// Scan sync structure = R8 (PROVEN, FROZEN): S1 / gates+drain / B2 /
// tid0 arrive(L2 atomic) / wv7 poll(L2 atomics) / S2 / stage / S3.
// R9: gate phase spread across all 8 waves (1 output/thread), h-first
// vmcnt(1) drain, xq prefetch after staging (off the drain path).

typedef __attribute__((ext_vector_type(4))) float f32x4;
typedef __attribute__((ext_vector_type(8))) short s16x8;
typedef __attribute__((ext_vector_type(4))) unsigned short u16x4;

static __device__ __forceinline__ unsigned short f2bf(float f) {
  union { float f; unsigned u; } v; v.f = f;
  unsigned u = v.u;
  u += 0x7FFFu + ((u >> 16) & 1u);   // RNE
  return (unsigned short)(u >> 16);
}
static __device__ __forceinline__ float bf2f(unsigned short h) {
  union { unsigned u; float f; } v; v.u = ((unsigned)h) << 16;
  return v.f;
}

// L2-scope (XCD-local) data ops
static __device__ __forceinline__ s16x8 ld16_l2(const unsigned short* p) {
  s16x8 r;
  asm volatile("global_load_dwordx4 %0, %1, off sc0" : "=v"(r) : "v"(p) : "memory");
  return r;
}
static __device__ __forceinline__ void st2_l2(unsigned short* p, unsigned short v) {
  unsigned vv = v;
  asm volatile("global_store_short %0, %1, off sc0" :: "v"(p), "v"(vv) : "memory");
}
// device-scope (MALL) data ops
static __device__ __forceinline__ s16x8 ld16_mall(const unsigned short* p) {
  s16x8 r;
  asm volatile("global_load_dwordx4 %0, %1, off sc0 sc1" : "=v"(r) : "v"(p) : "memory");
  return r;
}
static __device__ __forceinline__ void st2_mall(unsigned short* p, unsigned short v) {
  unsigned vv = v;
  asm volatile("global_store_short %0, %1, off sc0 sc1" :: "v"(p), "v"(vv) : "memory");
}
// det flags (once per launch): MALL loads/stores
static __device__ __forceinline__ void st_flag(unsigned int* p, unsigned v) {
  asm volatile("global_store_dword %0, %1, off sc0 sc1" :: "v"(p), "v"(v) : "memory");
}
static __device__ __forceinline__ unsigned ld_flag(const unsigned int* p) {
  unsigned r;
  asm volatile("global_load_dword %0, %1, off sc0 sc1\n\ts_waitcnt vmcnt(0)"
               : "=v"(r) : "v"(p) : "memory");
  return r;
}
// step-flag atomics (bypass vL1, execute at L2 / MALL with sc1)
static __device__ __forceinline__ void arrive_l2(unsigned int* p, unsigned v) {
  asm volatile("global_atomic_swap %0, %1, off" :: "v"(p), "v"(v) : "memory");
}
static __device__ __forceinline__ void arrive_mall(unsigned int* p, unsigned v) {
  asm volatile("global_atomic_swap %0, %1, off sc1" :: "v"(p), "v"(v) : "memory");
}
static __device__ __forceinline__ unsigned poll_l2(unsigned int* p, unsigned zero) {
  unsigned old;
  asm volatile("global_atomic_add %0, %1, %2, off sc0\n\ts_waitcnt vmcnt(0)"
               : "=v"(old) : "v"(p), "v"(zero) : "memory");
  return old;
}
static __device__ __forceinline__ unsigned poll_mall(unsigned int* p, unsigned zero) {
  unsigned old;
  asm volatile("global_atomic_add %0, %1, %2, off sc0 sc1\n\ts_waitcnt vmcnt(0)"
               : "=v"(old) : "v"(p), "v"(zero) : "memory");
  return old;
}

// ---------------- Phase 0: f32 -> bf16 convert ----------------
__global__ __launch_bounds__(256)
void cvt_bf16(const float* __restrict__ src, unsigned short* __restrict__ dst, int n4) {
  int i = blockIdx.x * 256 + threadIdx.x;
  int stride = gridDim.x * 256;
  for (; i < n4; i += stride) {
    f32x4 v = ((const f32x4*)src)[i];
    u16x4 o = { f2bf(v.x), f2bf(v.y), f2bf(v.z), f2bf(v.w) };
    ((u16x4*)dst)[i] = o;
  }
}

// ---------------- Phase 1: xg GEMM (bf16 in, bf16 out) ----------------
__global__ __launch_bounds__(256)
void xg_gemm(const unsigned short* __restrict__ Xb,  // [32768,1024] bf16
             const unsigned short* __restrict__ Wb,  // [3072,1024] bf16
             const float* __restrict__ bias,         // [3072]
             unsigned short* __restrict__ xg)        // [32768,3072] bf16
{
  __shared__ unsigned short Al[128][72];
  __shared__ unsigned short Bl[128][72];
  const int tid = threadIdx.x;
  const int lane = tid & 63;
  const int wv = tid >> 6;
  const int wm = (wv & 1) * 64;
  const int wn = (wv >> 1) * 64;
  const int m0 = blockIdx.y * 128;
  const int n0 = blockIdx.x * 128;
  const int r16 = lane & 15, r4 = lane >> 4;
  f32x4 acc[4][4] = {};

  for (int k0 = 0; k0 < 1024; k0 += 64) {
    __syncthreads();
    #pragma unroll
    for (int j = 0; j < 4; ++j) {
      int idx = j * 256 + tid;
      int row = idx >> 3, c8 = idx & 7;
      *(s16x8*)&Al[row][c8 * 8] = *(const s16x8*)(Xb + (size_t)(m0 + row) * 1024 + k0 + c8 * 8);
      *(s16x8*)&Bl[row][c8 * 8] = *(const s16x8*)(Wb + (size_t)(n0 + row) * 1024 + k0 + c8 * 8);
    }
    __syncthreads();
    #pragma unroll
    for (int kk = 0; kk < 64; kk += 32) {
      s16x8 af[4], bf[4];
      #pragma unroll
      for (int mi = 0; mi < 4; ++mi)
        af[mi] = *(const s16x8*)&Al[wm + mi * 16 + r16][kk + r4 * 8];
      #pragma unroll
      for (int ni = 0; ni < 4; ++ni)
        bf[ni] = *(const s16x8*)&Bl[wn + ni * 16 + r16][kk + r4 * 8];
      #pragma unroll
      for (int mi = 0; mi < 4; ++mi)
        #pragma unroll
        for (int ni = 0; ni < 4; ++ni)
          acc[mi][ni] = __builtin_amdgcn_mfma_f32_16x16x32_bf16(af[mi], bf[ni], acc[mi][ni], 0, 0, 0);
    }
  }
  #pragma unroll
  for (int ni = 0; ni < 4; ++ni) {
    float bv = bias[n0 + wn + ni * 16 + r16];
    #pragma unroll
    for (int mi = 0; mi < 4; ++mi) {
      #pragma unroll
      for (int r = 0; r < 4; ++r) {
        int m = m0 + wm + mi * 16 + r4 * 4 + r;
        int n = n0 + wn + ni * 16 + r16;
        xg[(size_t)m * 3072 + n] = f2bf(acc[mi][ni][r] + bv);
      }
    }
  }
}

// ---------------- Phase 2: persistent GRU scan ----------------
// 256 blocks: bg = id&7 (16 batch rows), cg = id>>3 (32 h-cols).
// 8 waves: ks = wv>>1 (K-quarter), nt = wv&1 (16-col half).
// Gates: spread over all 512 threads: row = tid>>5, col = tid&31.
__global__ __launch_bounds__(512, 2)
void gru_scan(const unsigned short* __restrict__ xg,  // [32768,3072] bf16
              const float* __restrict__ Whh,          // [3072,1024]
              const float* __restrict__ bhh,          // [3072]
              float* __restrict__ out,                // [256,128,1024]
              unsigned short* __restrict__ hbc,       // 2 x [128][1024] bf16
              unsigned int* __restrict__ bar)         // flag regions
{
  __shared__ char hraw[32768];           // swizzled [16][1024] bf16 h tile
  __shared__ float part[8][3][64][4];    // all 8 K-slices, lane-dense
  __shared__ int fastsh;

  const int tid = threadIdx.x;
  const int lane = tid & 63;
  const int wv = tid >> 6;
  const int id = blockIdx.x;
  const int bg = id & 7;
  const int cg = id >> 3;
  const int c0 = cg * 32;
  const int b0 = bg * 16;
  const int r16 = lane & 15, r4 = lane >> 4;
  const int ks = wv >> 1, nt = wv & 1;

  // step flags: one 128B line per (bg,cg) cell
  unsigned int* sflags = bar + (size_t)(bg * 32) * 32;   // + cg*32
  unsigned int* dflags = bar + 8192 + bg * 32;           // dense det flags

  // ---- XCD co-residency detection (HW_REG_XCC_ID) ----
  unsigned myxcc = (__builtin_amdgcn_s_getreg(63508) & 0xFu) | 0x100u;
  if (tid == 0) st_flag(dflags + cg, myxcc);
  if (wv == 0) {
    unsigned v;
    for (;;) {
      v = ld_flag(dflags + (lane & 31));
      if (__ballot(v < 0x100u) == 0) break;
      __builtin_amdgcn_s_sleep(1);
    }
    int bad = (v != myxcc);
    if (tid == 0) fastsh = (__ballot(bad) == 0) ? 1 : 0;
  }
  __syncthreads();
  const bool fast = (fastsh != 0);

  // ---- W_hh fragments in registers: bw[gate][kc] ----
  s16x8 bw[3][8];
  #pragma unroll
  for (int n = 0; n < 3; ++n) {
    const float* wrow = Whh + (size_t)(n * 1024 + c0 + nt * 16 + r16) * 1024;
    #pragma unroll
    for (int kc = 0; kc < 8; ++kc) {
      int k = ks * 256 + kc * 32 + r4 * 8;
      f32x4 v0 = *(const f32x4*)(wrow + k);
      f32x4 v1 = *(const f32x4*)(wrow + k + 4);
      s16x8 f;
      f[0] = (short)f2bf(v0.x); f[1] = (short)f2bf(v0.y);
      f[2] = (short)f2bf(v0.z); f[3] = (short)f2bf(v0.w);
      f[4] = (short)f2bf(v1.x); f[5] = (short)f2bf(v1.y);
      f[6] = (short)f2bf(v1.z); f[7] = (short)f2bf(v1.w);
      bw[n][kc] = f;
    }
  }

  // ---- gate-phase constants: one output (row,col) per thread ----
  const int grow = tid >> 5;          // 0..15
  const int gcolL = tid & 31;         // 0..31
  const int gcol = c0 + gcolL;
  const int g_nt = gcolL >> 4, g_c16 = gcolL & 15;
  const int g_lane = (grow >> 2) * 16 + g_c16;
  const int g_rg = grow & 3;
  const float bR = bhh[gcol];
  const float bZ = bhh[1024 + gcol];
  const float bN = bhh[2048 + gcol];
  float hprev = 0.f;
  float xr, xz, xn;
  {
    size_t xi = ((size_t)(b0 + grow)) * 3072 + gcol;
    xr = bf2f(xg[xi]); xz = bf2f(xg[xi + 1024]); xn = bf2f(xg[xi + 2048]);
  }

  // zero h tile (h0 = 0)
  #pragma unroll
  for (int i = 0; i < 4; ++i)
    *(f32x4*)(hraw + tid * 64 + i * 16) = (f32x4){0.f, 0.f, 0.f, 0.f};
  __syncthreads();

  // A-frag read addressing (swizzled)
  const int arow = lane & 15;
  const int aswz = (arow & 7) << 4;
  const int abase = arow * 2048;
  const int g16 = (lane >> 4) * 16;

  // staging addressing: rows {i*4+ks}, colbyte = nt*1024 + lane*16
  const int scb = nt * 1024 + lane * 16;
  int s_goff[4], s_loff[4];
  #pragma unroll
  for (int i = 0; i < 4; ++i) {
    int row = i * 4 + ks;
    s_goff[i] = (b0 + row) * 1024 + (scb >> 1);
    s_loff[i] = row * 2048 + (scb ^ ((row & 7) << 4));
  }

  for (int t = 0; t < 256; ++t) {
    // ---- MFMA over h[t] ----
    f32x4 a0 = {0.f,0.f,0.f,0.f}, a1 = a0, a2 = a0;
    #pragma unroll
    for (int kc = 0; kc < 8; ++kc) {
      s16x8 a = *(const s16x8*)(hraw + abase + ((ks * 512 + kc * 64 + g16) ^ aswz));
      a0 = __builtin_amdgcn_mfma_f32_16x16x32_bf16(a, bw[0][kc], a0, 0, 0, 0);
      a1 = __builtin_amdgcn_mfma_f32_16x16x32_bf16(a, bw[1][kc], a1, 0, 0, 0);
      a2 = __builtin_amdgcn_mfma_f32_16x16x32_bf16(a, bw[2][kc], a2, 0, 0, 0);
    }
    {
      int pi = ks * 2 + nt;
      *(f32x4*)&part[pi][0][lane][0] = a0;
      *(f32x4*)&part[pi][1][lane][0] = a1;
      *(f32x4*)&part[pi][2][lane][0] = a2;
    }
    __syncthreads();                                   // S1

    // ---- gates: every thread owns (grow, gcolL) ----
    {
      float sr = bR, sz = bZ, sn = bN;
      #pragma unroll
      for (int kx = 0; kx < 4; ++kx) {
        sr += part[kx * 2 + g_nt][0][g_lane][g_rg];
        sz += part[kx * 2 + g_nt][1][g_lane][g_rg];
        sn += part[kx * 2 + g_nt][2][g_lane][g_rg];
      }
      float rg = 1.f / (1.f + expf(-(xr + sr)));
      float zg = 1.f / (1.f + expf(-(xz + sz)));
      float ng = tanhf(xn + rg * sn);
      float h = (1.f - zg) * ng + zg * hprev;
      hprev = h;
      unsigned short* wH = hbc + (size_t)((t + 1) & 1) * 131072;
      size_t widx = (size_t)(b0 + grow) * 1024 + gcol;
      if (fast) st2_l2(wH + widx, f2bf(h));
      else      st2_mall(wH + widx, f2bf(h));
      out[(size_t)t * 131072 + widx] = h;              // after h store (program order)
      asm volatile("s_waitcnt vmcnt(1)" ::: "memory"); // h acked; out in flight
    }
    __syncthreads();                                   // B2

    if (tid == 0) {
      if (fast) arrive_l2(sflags + cg * 32, (unsigned)(t + 1));
      else      arrive_mall(sflags + cg * 32, (unsigned)(t + 1));
    }

    if (t < 255) {
      // wv7 polls 32 per-block flags via L2/MALL atomics (arrive precedes poll!)
      if (wv == 7 && lane < 32) {
        unsigned tgt = (unsigned)(t + 1);
        unsigned int* fp = sflags + lane * 32;
        if (fast) {
          for (;;) {
            unsigned v = poll_l2(fp, 0u);
            if (__ballot(v < tgt) == 0) break;
          }
        } else {
          for (;;) {
            unsigned v = poll_mall(fp, 0u);
            if (__ballot(v < tgt) == 0) break;
            __builtin_amdgcn_s_sleep(1);
          }
        }
      }
      __syncthreads();                                 // S2

      // stage h[t+1] into LDS (swizzled)
      const unsigned short* hs = hbc + (size_t)((t + 1) & 1) * 131072;
      s16x8 v0, v1, v2, v3;
      if (fast) {
        v0 = ld16_l2(hs + s_goff[0]); v1 = ld16_l2(hs + s_goff[1]);
        v2 = ld16_l2(hs + s_goff[2]); v3 = ld16_l2(hs + s_goff[3]);
      } else {
        v0 = ld16_mall(hs + s_goff[0]); v1 = ld16_mall(hs + s_goff[1]);
        v2 = ld16_mall(hs + s_goff[2]); v3 = ld16_mall(hs + s_goff[3]);
      }
      asm volatile("s_waitcnt vmcnt(0)" ::: "memory");
      *(s16x8*)(hraw + s_loff[0]) = v0;
      *(s16x8*)(hraw + s_loff[1]) = v1;
      *(s16x8*)(hraw + s_loff[2]) = v2;
      *(s16x8*)(hraw + s_loff[3]) = v3;

      // xg prefetch for t+1 — AFTER the staging drain, so it never blocks it
      {
        size_t xi = ((size_t)((t + 1) * 128 + b0 + grow)) * 3072 + gcol;
        xr = bf2f(xg[xi]); xz = bf2f(xg[xi + 1024]); xn = bf2f(xg[xi + 2048]);
      }
      __syncthreads();                                 // S3
    }
  }
}

extern "C" void kernel_launch(void* const* d_in, const int* in_sizes, int n_in,
                              void* d_out, int out_size, void* d_ws, size_t ws_size,
                              hipStream_t stream) {
  const float* x   = (const float*)d_in[0];
  const float* wih = (const float*)d_in[1];
  const float* whh = (const float*)d_in[2];
  const float* bih = (const float*)d_in[3];
  const float* bhh = (const float*)d_in[4];
  float* out = (float*)d_out;

  char* ws = (char*)d_ws;
  unsigned short* xg  = (unsigned short*)ws;                      // 192 MiB
  unsigned short* xbf = (unsigned short*)(ws + 201326592);        // 64 MiB
  unsigned short* wbf = (unsigned short*)(ws + 268435456);        // 6 MiB
  unsigned short* hbc = (unsigned short*)(ws + 274726912);        // 512 KiB
  unsigned int*   bar = (unsigned int*)(ws + 275251200);          // 40 KiB

  hipMemsetAsync(bar, 0, 40960, stream);
  cvt_bf16<<<2048, 256, 0, stream>>>(x, xbf, 32768 * 1024 / 4);
  cvt_bf16<<<768, 256, 0, stream>>>(wih, wbf, 3072 * 1024 / 4);
  xg_gemm<<<dim3(24, 256), 256, 0, stream>>>(xbf, wbf, bih, xg);
  gru_scan<<<256, 512, 0, stream>>>(xg, whh, bhh, out, hbc, bar);
}